// Round 2
// baseline (576.490 us; speedup 1.0000x reference)
//
#include <hip/hip_runtime.h>

// Problem constants (fixed by setup_inputs in the reference).
#define NIMG 4
#define CCH  256
#define HDIM 200
#define WDIM 272
#define OSZ  7

// ---------------------------------------------------------------------------
// K1: per-(n,h) block, thread = channel c. Sequential prefix-sum along W
// (float4 reads from the thread's own contiguous row -> L1-resident lines),
// writes into channels-last integral buffer integ[n][h][w][c] (coalesced:
// 256 threads * 4B = 1KB contiguous per w step).
// ---------------------------------------------------------------------------
__global__ __launch_bounds__(256) void k_rowscan(const float* __restrict__ fm,
                                                 float* __restrict__ integ) {
    const int c = threadIdx.x;           // 0..255
    const int b = blockIdx.x;            // n*HDIM + h
    const int n = b / HDIM;
    const int h = b % HDIM;

    const float4* src = reinterpret_cast<const float4*>(
        fm + ((size_t)((n * CCH + c) * HDIM + h)) * WDIM);
    float* dst = integ + ((size_t)(n * HDIM + h) * WDIM) * CCH + c;

    float acc = 0.0f;
#pragma unroll 4
    for (int w4 = 0; w4 < WDIM / 4; ++w4) {
        float4 v = src[w4];
        float a0 = acc + v.x;
        float a1 = a0 + v.y;
        float a2 = a1 + v.z;
        float a3 = a2 + v.w;
        size_t wb = (size_t)(w4 * 4) * CCH;
        dst[wb]            = a0;
        dst[wb + CCH]      = a1;
        dst[wb + 2 * CCH]  = a2;
        dst[wb + 3 * CCH]  = a3;
        acc = a3;
    }
}

// ---------------------------------------------------------------------------
// K2: column scan along H. Thread = (n, w, c4) handling 4 consecutive
// channels as float4. Reads/writes 16B per lane, coalesced across the
// channel-fastest layout. Exactly NIMG*WDIM*64 = 69632 threads = 272 blocks.
// Unrolled x2 so two independent loads are in flight per dependent step
// (only ~4 waves/CU of TLP here, so ILP must cover HBM latency).
// ---------------------------------------------------------------------------
__global__ __launch_bounds__(256) void k_colscan(float4* __restrict__ integ4) {
    const int C4 = CCH / 4;              // 64
    int t = blockIdx.x * 256 + threadIdx.x;
    int c4 = t & (C4 - 1);
    int rest = t >> 6;                   // n*WDIM + w
    int w = rest % WDIM;
    int n = rest / WDIM;

    const int stride = WDIM * C4;        // elements per h step
    int idx = ((n * HDIM) * WDIM + w) * C4 + c4;

    float4 run = make_float4(0.f, 0.f, 0.f, 0.f);
    for (int h = 0; h < HDIM; h += 2) {
        float4 v0 = integ4[idx];
        float4 v1 = integ4[idx + stride];
        run.x += v0.x; run.y += v0.y; run.z += v0.z; run.w += v0.w;
        integ4[idx] = run;
        run.x += v1.x; run.y += v1.y; run.z += v1.z; run.w += v1.w;
        integ4[idx + stride] = run;
        idx += 2 * stride;
    }
}

// ---------------------------------------------------------------------------
// K3: pooling. Block = (roi, i, j); thread = channel. All ROI/bin math is
// wave-uniform (SALU). 4 corner loads, each coalesced (256 threads read
// 1KB contiguous from channels-last integral). One scattered 4B store
// (merged in L2). Also writes img_idx (as float) for output 0.
// ---------------------------------------------------------------------------
__global__ __launch_bounds__(256) void k_pool(const float* __restrict__ integ,
                                              const int* __restrict__ rois,
                                              float* __restrict__ out, int R) {
    const int b  = blockIdx.x;
    const int r  = b / (OSZ * OSZ);
    const int ij = b % (OSZ * OSZ);
    const int i  = ij / OSZ;
    const int j  = ij % OSZ;
    const int c  = threadIdx.x;

    const int* rp = rois + r * 5;
    const int n  = rp[0];
    const int x1 = rp[1], y1 = rp[2], x2 = rp[3], y2 = rp[4];
    const int h_in = y2 - y1 + 1;
    const int w_in = x2 - x1 + 1;

    // torch AdaptiveAvgPool2d bin boundaries (matches reference exactly)
    const int hs = y1 + (i * h_in) / OSZ;
    const int he = y1 + ((i + 1) * h_in + OSZ - 1) / OSZ;
    const int ws = x1 + (j * w_in) / OSZ;
    const int we = x1 + ((j + 1) * w_in + OSZ - 1) / OSZ;

    const float inv_area = 1.0f / (float)((he - hs) * (we - ws));

    const int hi = he - 1, hl = hs - 1;
    const int wi = we - 1, wl = ws - 1;

    const float* base = integ + (size_t)n * HDIM * WDIM * CCH + c;

    // inclusive integral: I(h,w) = sum fm[0..h][0..w]; I(-1,*) = I(*,-1) = 0
    float A = base[((size_t)hi * WDIM + wi) * CCH];
    float B = (hl >= 0) ? base[((size_t)hl * WDIM + wi) * CCH] : 0.0f;
    float Cv = (wl >= 0) ? base[((size_t)hi * WDIM + wl) * CCH] : 0.0f;
    float D = (hl >= 0 && wl >= 0) ? base[((size_t)hl * WDIM + wl) * CCH] : 0.0f;

    float s = (A - B) - (Cv - D);
    out[R + (((size_t)r * CCH + c) * OSZ + i) * OSZ + j] = s * inv_area;

    if (ij == 0 && c == 0) out[r] = (float)n;
}

// ---------------------------------------------------------------------------
// Fallback: direct summation (no workspace). Block = (roi,i,j), thread = c.
// Only used if ws_size is too small for the integral image.
// ---------------------------------------------------------------------------
__global__ __launch_bounds__(256) void k_direct(const float* __restrict__ fm,
                                                const int* __restrict__ rois,
                                                float* __restrict__ out, int R) {
    const int b  = blockIdx.x;
    const int r  = b / (OSZ * OSZ);
    const int ij = b % (OSZ * OSZ);
    const int i  = ij / OSZ;
    const int j  = ij % OSZ;
    const int c  = threadIdx.x;

    const int* rp = rois + r * 5;
    const int n  = rp[0];
    const int x1 = rp[1], y1 = rp[2], x2 = rp[3], y2 = rp[4];
    const int h_in = y2 - y1 + 1;
    const int w_in = x2 - x1 + 1;

    const int hs = y1 + (i * h_in) / OSZ;
    const int he = y1 + ((i + 1) * h_in + OSZ - 1) / OSZ;
    const int ws = x1 + (j * w_in) / OSZ;
    const int we = x1 + ((j + 1) * w_in + OSZ - 1) / OSZ;

    const float inv_area = 1.0f / (float)((he - hs) * (we - ws));

    const float* p = fm + (size_t)(n * CCH + c) * HDIM * WDIM;
    float acc = 0.0f;
    for (int h = hs; h < he; ++h) {
        const float* row = p + (size_t)h * WDIM;
        for (int w = ws; w < we; ++w) acc += row[w];
    }
    out[R + (((size_t)r * CCH + c) * OSZ + i) * OSZ + j] = acc * inv_area;

    if (ij == 0 && c == 0) out[r] = (float)n;
}

extern "C" void kernel_launch(void* const* d_in, const int* in_sizes, int n_in,
                              void* d_out, int out_size, void* d_ws, size_t ws_size,
                              hipStream_t stream) {
    const float* fm  = (const float*)d_in[0];
    const int* rois  = (const int*)d_in[1];
    float* out       = (float*)d_out;
    const int R      = in_sizes[1] / 5;   // 1000

    const size_t need = (size_t)NIMG * HDIM * WDIM * CCH * sizeof(float); // ~223 MB

    if (ws_size >= need) {
        float* integ = (float*)d_ws;
        k_rowscan<<<NIMG * HDIM, 256, 0, stream>>>(fm, integ);
        k_colscan<<<(NIMG * WDIM * (CCH / 4)) / 256, 256, 0, stream>>>((float4*)integ);
        k_pool<<<R * OSZ * OSZ, 256, 0, stream>>>(integ, rois, out, R);
    } else {
        k_direct<<<R * OSZ * OSZ, 256, 0, stream>>>(fm, rois, out, R);
    }
}

// Round 5
// 502.918 us; speedup vs baseline: 1.1463x; 1.1463x over previous
//
#include <hip/hip_runtime.h>

// Problem constants (fixed by setup_inputs in the reference).
#define NIMG 4
#define CCH  256
#define HDIM 200
#define WDIM 272
#define OSZ  7

// ---------------------------------------------------------------------------
// K1: row prefix-scan, W split into 2 halves per (n,h) for 2x parallelism
// (1600 blocks -> ~25 waves/CU vs 12.5 before). Thread = channel c.
// Left-half blocks write their row-total to corr[n][h][c]; the column-scan
// adds it back for right-half columns. Reads: own-row sequential float4
// (L1-resident lines). Writes: channels-last, 256 threads * 4B contiguous.
// ---------------------------------------------------------------------------
__global__ __launch_bounds__(256) void k_rowscan_half(const float* __restrict__ fm,
                                                      float* __restrict__ integ,
                                                      float* __restrict__ corr) {
    const int c    = threadIdx.x;        // 0..255
    const int b    = blockIdx.x;         // (n*HDIM + h)*2 + half
    const int half = b & 1;
    const int nh   = b >> 1;
    const int n    = nh / HDIM;
    const int h    = nh % HDIM;
    const int HW   = WDIM / 2;           // 136 (multiple of 4; 16B-aligned offset)

    const float4* src = reinterpret_cast<const float4*>(
        fm + ((size_t)((n * CCH + c) * HDIM + h)) * WDIM + half * HW);
    float* dst = integ + ((size_t)((n * HDIM + h) * WDIM) + half * HW) * CCH + c;

    float acc = 0.0f;
#pragma unroll 2
    for (int w4 = 0; w4 < HW / 4; ++w4) {     // 34 iterations
        float4 v = src[w4];
        float a0 = acc + v.x;
        float a1 = a0 + v.y;
        float a2 = a1 + v.z;
        float a3 = a2 + v.w;
        size_t wb = (size_t)(w4 * 4) * CCH;
        dst[wb]           = a0;
        dst[wb + CCH]     = a1;
        dst[wb + 2 * CCH] = a2;
        dst[wb + 3 * CCH] = a3;
        acc = a3;
    }
    if (half == 0) corr[(size_t)(n * HDIM + h) * CCH + c] = acc;
}

// Fallback full-row scan (used when ws has no room for corr).
__global__ __launch_bounds__(256) void k_rowscan_full(const float* __restrict__ fm,
                                                      float* __restrict__ integ) {
    const int c = threadIdx.x;
    const int b = blockIdx.x;            // n*HDIM + h
    const int n = b / HDIM;
    const int h = b % HDIM;

    const float4* src = reinterpret_cast<const float4*>(
        fm + ((size_t)((n * CCH + c) * HDIM + h)) * WDIM);
    float* dst = integ + ((size_t)(n * HDIM + h) * WDIM) * CCH + c;

    float acc = 0.0f;
#pragma unroll 2
    for (int w4 = 0; w4 < WDIM / 4; ++w4) {
        float4 v = src[w4];
        float a0 = acc + v.x;
        float a1 = a0 + v.y;
        float a2 = a1 + v.z;
        float a3 = a2 + v.w;
        size_t wb = (size_t)(w4 * 4) * CCH;
        dst[wb]           = a0;
        dst[wb + CCH]     = a1;
        dst[wb + 2 * CCH] = a2;
        dst[wb + 3 * CCH] = a3;
        acc = a3;
    }
}

// ---------------------------------------------------------------------------
// K2: column scan along H, scalar thread = (n, w, c). 1088 blocks
// (~17 waves/CU, 4x the old float4 version's TLP). Unroll-8 puts up to 16
// independent loads in flight per dependent-chain step. For right-half
// columns (HASCORR), adds the left-half row totals so the stored integral
// is the true full-row prefix before H-accumulation.
// ---------------------------------------------------------------------------
template <bool HASCORR>
__global__ __launch_bounds__(256) void k_colscan2(float* __restrict__ integ,
                                                  const float* __restrict__ corr) {
    const int b = blockIdx.x;            // n*WDIM + w
    const int n = b / WDIM;
    const int w = b % WDIM;
    const int c = threadIdx.x;
    const int S = WDIM * CCH;            // element stride per h step

    float* p = integ + ((size_t)(n * HDIM) * WDIM + w) * CCH + c;
    const float* cp = corr + (size_t)(n * HDIM) * CCH + c;
    const bool right = HASCORR && (w >= WDIM / 2);

    float run = 0.0f;
    for (int h = 0; h < HDIM; h += 8) {  // 200 % 8 == 0
        float v[8], u[8];
#pragma unroll
        for (int k = 0; k < 8; ++k) v[k] = p[(size_t)(h + k) * S];
#pragma unroll
        for (int k = 0; k < 8; ++k) u[k] = right ? cp[(size_t)(h + k) * CCH] : 0.0f;
#pragma unroll
        for (int k = 0; k < 8; ++k) {
            run += v[k] + u[k];
            p[(size_t)(h + k) * S] = run;
        }
    }
}

// ---------------------------------------------------------------------------
// K3: pooling, block = ROI, thread = channel. All 49 bins fully unrolled:
// 196 independent coalesced corner loads per thread (bin boundaries shared
// between adjacent bins hit L1), then each thread stores its 49 outputs
// contiguously -> one block covers a contiguous ~50KB output region, so L2
// write-combines full lines (fixes cross-XCD partial-line write scatter).
// All array indices compile-time constant (no scratch spill).
// ---------------------------------------------------------------------------
__global__ __launch_bounds__(256) void k_pool2(const float* __restrict__ integ,
                                               const int* __restrict__ rois,
                                               float* __restrict__ out, int R) {
    const int r = blockIdx.x;
    const int c = threadIdx.x;

    const int* rp = rois + r * 5;
    const int n  = rp[0];
    const int x1 = rp[1], y1 = rp[2], x2 = rp[3], y2 = rp[4];
    const int h_in = y2 - y1 + 1;
    const int w_in = x2 - x1 + 1;

    const float* base = integ + (size_t)n * HDIM * WDIM * CCH + c;

    float res[OSZ * OSZ];
#pragma unroll
    for (int i = 0; i < OSZ; ++i) {
        const int hs = y1 + (i * h_in) / OSZ;
        const int he = y1 + ((i + 1) * h_in + OSZ - 1) / OSZ;
        const int hl = hs - 1;
        const size_t rhi = (size_t)(he - 1) * WDIM;
        const size_t rhl = (size_t)hl * WDIM;          // used only if hl >= 0
#pragma unroll
        for (int j = 0; j < OSZ; ++j) {
            const int ws = x1 + (j * w_in) / OSZ;
            const int we = x1 + ((j + 1) * w_in + OSZ - 1) / OSZ;
            const int wl = ws - 1;
            const int wi = we - 1;
            float A  = base[(rhi + wi) * CCH];
            float B  = (hl >= 0) ? base[(rhl + wi) * CCH] : 0.0f;
            float Cv = (wl >= 0) ? base[(rhi + wl) * CCH] : 0.0f;
            float D  = (hl >= 0 && wl >= 0) ? base[(rhl + wl) * CCH] : 0.0f;
            const float inv_area = 1.0f / (float)((he - hs) * (we - ws));
            res[i * OSZ + j] = ((A - B) - (Cv - D)) * inv_area;
        }
    }

    float* po = out + R + (size_t)(r * CCH + c) * (OSZ * OSZ);
#pragma unroll
    for (int k = 0; k < OSZ * OSZ; ++k) po[k] = res[k];

    if (c == 0) out[r] = (float)n;
}

// ---------------------------------------------------------------------------
// Fallback: direct summation (no workspace).
// ---------------------------------------------------------------------------
__global__ __launch_bounds__(256) void k_direct(const float* __restrict__ fm,
                                                const int* __restrict__ rois,
                                                float* __restrict__ out, int R) {
    const int b  = blockIdx.x;
    const int r  = b / (OSZ * OSZ);
    const int ij = b % (OSZ * OSZ);
    const int i  = ij / OSZ;
    const int j  = ij % OSZ;
    const int c  = threadIdx.x;

    const int* rp = rois + r * 5;
    const int n  = rp[0];
    const int x1 = rp[1], y1 = rp[2], x2 = rp[3], y2 = rp[4];
    const int h_in = y2 - y1 + 1;
    const int w_in = x2 - x1 + 1;

    const int hs = y1 + (i * h_in) / OSZ;
    const int he = y1 + ((i + 1) * h_in + OSZ - 1) / OSZ;
    const int ws = x1 + (j * w_in) / OSZ;
    const int we = x1 + ((j + 1) * w_in + OSZ - 1) / OSZ;

    const float inv_area = 1.0f / (float)((he - hs) * (we - ws));

    const float* p = fm + (size_t)(n * CCH + c) * HDIM * WDIM;
    float acc = 0.0f;
    for (int h = hs; h < he; ++h) {
        const float* row = p + (size_t)h * WDIM;
        for (int w = ws; w < we; ++w) acc += row[w];
    }
    out[R + (((size_t)r * CCH + c) * OSZ + i) * OSZ + j] = acc * inv_area;

    if (ij == 0 && c == 0) out[r] = (float)n;
}

extern "C" void kernel_launch(void* const* d_in, const int* in_sizes, int n_in,
                              void* d_out, int out_size, void* d_ws, size_t ws_size,
                              hipStream_t stream) {
    const float* fm  = (const float*)d_in[0];
    const int* rois  = (const int*)d_in[1];
    float* out       = (float*)d_out;
    const int R      = in_sizes[1] / 5;   // 1000

    const size_t need_integ = (size_t)NIMG * HDIM * WDIM * CCH * sizeof(float); // 222.8 MB
    const size_t need_corr  = (size_t)NIMG * HDIM * CCH * sizeof(float);        // 0.8 MB

    if (ws_size >= need_integ + need_corr) {
        float* integ = (float*)d_ws;
        float* corr  = integ + (size_t)NIMG * HDIM * WDIM * CCH;
        k_rowscan_half<<<NIMG * HDIM * 2, 256, 0, stream>>>(fm, integ, corr);
        k_colscan2<true><<<NIMG * WDIM, 256, 0, stream>>>(integ, corr);
        k_pool2<<<R, 256, 0, stream>>>(integ, rois, out, R);
    } else if (ws_size >= need_integ) {
        float* integ = (float*)d_ws;
        k_rowscan_full<<<NIMG * HDIM, 256, 0, stream>>>(fm, integ);
        k_colscan2<false><<<NIMG * WDIM, 256, 0, stream>>>(integ, integ);
        k_pool2<<<R, 256, 0, stream>>>(integ, rois, out, R);
    } else {
        k_direct<<<R * OSZ * OSZ, 256, 0, stream>>>(fm, rois, out, R);
    }
}